// Round 10
// baseline (1372.822 us; speedup 1.0000x reference)
//
#include <hip/hip_runtime.h>
#include <cstddef>
#include <cstdint>

#define Tn 512
#define Bn 512

__device__ __forceinline__ float rlane(float v, int lane) {
    return __uint_as_float((unsigned)__builtin_amdgcn_readlane((int)__float_as_uint(v), lane));
}
__device__ __forceinline__ float sigm(float x) { return 1.0f / (1.0f + __expf(-x)); }
// tanh(x) = 1 - 2/(1+e^{2x}); inf-safe at both ends
__device__ __forceinline__ float tanhf_(float x) { return 1.0f - 2.0f / (1.0f + __expf(2.0f * x)); }

// LDS-visibility barrier WITHOUT the __syncthreads vmcnt(0) drain.
#define BAR_LGKM() asm volatile("s_waitcnt lgkmcnt(0)\n\ts_barrier" ::: "memory")

// ---------------------------------------------------------------------------
// Layer 0 (IN=1). ONE WAVE per b-PAIR per direction: 2 independent chains
// interleaved in a single instruction stream, NO barrier, weights SHARED
// (w[g][k] fetched once feeds both chains' fmas). The two recurrences
// overlap each other's stalls (readlane issue, fma dep-chains, activation
// latency). 512 blocks x 1 wave = 2 waves/CU.
// Weight storage class is left to the compiler (AGPR banking is benign —
// R8/R9 evidence; PIN hurt only via occupancy).
// ---------------------------------------------------------------------------
__global__ __launch_bounds__(64, 1) void k_lstm_l0(
    const float* __restrict__ x,
    const float* __restrict__ wih_f, const float* __restrict__ whh_f,
    const float* __restrict__ bih_f, const float* __restrict__ bhh_f,
    const float* __restrict__ wih_r, const float* __restrict__ whh_r,
    const float* __restrict__ bih_r, const float* __restrict__ bhh_r,
    float* __restrict__ h0out)
{
    const int j   = threadIdx.x;           // hidden unit
    const int bp  = blockIdx.x >> 1;       // batch pair
    const int dir = blockIdx.x & 1;
    const int b0  = bp * 2;
    const int b1  = b0 + 1;

    const float* __restrict__ wih = dir ? wih_r : wih_f;
    const float* __restrict__ whh = dir ? whh_r : whh_f;
    const float* __restrict__ bih = dir ? bih_r : bih_f;
    const float* __restrict__ bhh = dir ? bhh_r : bhh_f;

    __shared__ float xs[2][Tn];   // 4 KB; single wave -> no barrier needed
    #pragma unroll
    for (int i = 0; i < Tn / 64; ++i) {
        xs[0][i * 64 + j] = x[(size_t)b0 * Tn + i * 64 + j];
        xs[1][i * 64 + j] = x[(size_t)b1 * Tn + i * 64 + j];
    }

    // per-lane weights: w[g][k] = w_hh[g*64+j][k] (storage class = compiler's)
    float w[4][64];
    float wx[4], bias[4];
    #pragma unroll
    for (int g = 0; g < 4; ++g) {
        const int r = g * 64 + j;
        wx[g]   = wih[r];                  // IN == 1
        bias[g] = bih[r] + bhh[r];
        #pragma unroll
        for (int k4 = 0; k4 < 16; ++k4) {
            const float4 v = *reinterpret_cast<const float4*>(&whh[(size_t)r * 64 + k4 * 4]);
            w[g][k4 * 4 + 0] = v.x; w[g][k4 * 4 + 1] = v.y;
            w[g][k4 * 4 + 2] = v.z; w[g][k4 * 4 + 3] = v.w;
        }
    }

    float hA = 0.0f, cA = 0.0f, hB = 0.0f, cB = 0.0f;
    float* __restrict__ opA = h0out + (size_t)b0 * Tn * 128 + dir * 64 + j;
    float* __restrict__ opB = h0out + (size_t)b1 * Tn * 128 + dir * 64 + j;

    for (int s = 0; s < Tn; ++s) {
        const int t = dir ? (Tn - 1 - s) : s;
        const float xtA = xs[0][t];
        const float xtB = xs[1][t];

        float aA0 = fmaf(xtA, wx[0], bias[0]);
        float aA1 = fmaf(xtA, wx[1], bias[1]);
        float aA2 = fmaf(xtA, wx[2], bias[2]);
        float aA3 = fmaf(xtA, wx[3], bias[3]);
        float aB0 = fmaf(xtB, wx[0], bias[0]);
        float aB1 = fmaf(xtB, wx[1], bias[1]);
        float aB2 = fmaf(xtB, wx[2], bias[2]);
        float aB3 = fmaf(xtB, wx[3], bias[3]);
        #pragma unroll
        for (int k = 0; k < 64; ++k) {
            const float vA = rlane(hA, k);
            const float vB = rlane(hB, k);
            const float w0 = w[0][k], w1 = w[1][k], w2 = w[2][k], w3 = w[3][k];
            aA0 = fmaf(vA, w0, aA0);  aB0 = fmaf(vB, w0, aB0);
            aA1 = fmaf(vA, w1, aA1);  aB1 = fmaf(vB, w1, aB1);
            aA2 = fmaf(vA, w2, aA2);  aB2 = fmaf(vB, w2, aB2);
            aA3 = fmaf(vA, w3, aA3);  aB3 = fmaf(vB, w3, aB3);
        }
        cA = sigm(aA1) * cA + sigm(aA0) * tanhf_(aA2);
        hA = sigm(aA3) * tanhf_(cA);
        cB = sigm(aB1) * cB + sigm(aB0) * tanhf_(aB2);
        hB = sigm(aB3) * tanhf_(cB);
        opA[(size_t)t * 128] = hA;     // stores ride vmcnt, never waited
        opB[(size_t)t * 128] = hB;
    }
}

// ---------------------------------------------------------------------------
// Layer 1 forward scan — VERBATIM Round-9 config (measured ~526 us):
// (512,2), 2 batch elements x 4 waves, K=192 split 48/wave,
//   wv0: x1a[0:48)  wv1: x1a[48:64)+x1b[0:32)
//   wv2: x1b[32:64)+h[0:16)  wv3: h[16:64)
// Waves 0,1 pure producers w/ 1-step prefetch; waves 2,3 redundantly reduce
// all 4 partials in fixed order + activate. One lgkm-only barrier per step.
// ---------------------------------------------------------------------------
__global__ __launch_bounds__(512, 2) void k_lstm_l1f(
    const float* __restrict__ h0,
    const float* __restrict__ wih, const float* __restrict__ whh,
    const float* __restrict__ bih, const float* __restrict__ bhh,
    float* __restrict__ h1last)
{
    const int tid = threadIdx.x;
    const int e   = tid >> 8;        // batch element in block
    const int wv  = (tid >> 6) & 3;  // 0..3
    const int j   = tid & 63;
    const int b   = blockIdx.x * 2 + e;
    const int kbase = wv * 48;

    __shared__ float4 part[2][2][4][64];   // [e][buf][wv][unit], 16 KB

    float bias[4];
    #pragma unroll
    for (int g = 0; g < 4; ++g) {
        const int r = g * 64 + j;
        bias[g] = bih[r] + bhh[r];
    }

    float wt[4][48];
    #pragma unroll
    for (int g = 0; g < 4; ++g) {
        const int r = g * 64 + j;
        #pragma unroll
        for (int k4 = 0; k4 < 12; ++k4) {
            const int k = kbase + k4 * 4;
            const float* __restrict__ src = (k < 128)
                ? (wih + (size_t)r * 128 + k)
                : (whh + (size_t)r * 64 + (k - 128));
            const float4 w4 = *reinterpret_cast<const float4*>(src);
            wt[g][k4 * 4 + 0] = w4.x; wt[g][k4 * 4 + 1] = w4.y;
            wt[g][k4 * 4 + 2] = w4.z; wt[g][k4 * 4 + 3] = w4.w;
        }
    }

    const float* __restrict__ xrow = h0 + (size_t)b * Tn * 128;

    float x1a = 0.0f, x1b = 0.0f;
    if (wv <= 1) x1a = xrow[j];
    if (wv == 1 || wv == 2) x1b = xrow[64 + j];
    float h = 0.0f, c = 0.0f;

    for (int t = 0; t < Tn; ++t) {
        const int bf = t & 1;
        const int tn = (t + 1 < Tn) ? (t + 1) : t;
        float nx1a = x1a, nx1b = x1b;
        if (wv <= 1)            nx1a = xrow[(size_t)tn * 128 + j];
        if (wv == 1 || wv == 2) nx1b = xrow[(size_t)tn * 128 + 64 + j];

        float a0 = 0.0f, a1 = 0.0f, a2 = 0.0f, a3 = 0.0f;
        if (wv == 0) {
            #pragma unroll
            for (int kk = 0; kk < 48; ++kk) {
                const float v = rlane(x1a, kk);
                a0 = fmaf(v, wt[0][kk], a0); a1 = fmaf(v, wt[1][kk], a1);
                a2 = fmaf(v, wt[2][kk], a2); a3 = fmaf(v, wt[3][kk], a3);
            }
        } else if (wv == 1) {
            #pragma unroll
            for (int kk = 0; kk < 48; ++kk) {
                const float v = (kk < 16) ? rlane(x1a, 48 + kk) : rlane(x1b, kk - 16);
                a0 = fmaf(v, wt[0][kk], a0); a1 = fmaf(v, wt[1][kk], a1);
                a2 = fmaf(v, wt[2][kk], a2); a3 = fmaf(v, wt[3][kk], a3);
            }
        } else if (wv == 2) {
            #pragma unroll
            for (int kk = 0; kk < 48; ++kk) {
                const float v = (kk < 32) ? rlane(x1b, 32 + kk) : rlane(h, kk - 32);
                a0 = fmaf(v, wt[0][kk], a0); a1 = fmaf(v, wt[1][kk], a1);
                a2 = fmaf(v, wt[2][kk], a2); a3 = fmaf(v, wt[3][kk], a3);
            }
        } else {
            #pragma unroll
            for (int kk = 0; kk < 48; ++kk) {
                const float v = rlane(h, 16 + kk);
                a0 = fmaf(v, wt[0][kk], a0); a1 = fmaf(v, wt[1][kk], a1);
                a2 = fmaf(v, wt[2][kk], a2); a3 = fmaf(v, wt[3][kk], a3);
            }
        }
        part[e][bf][wv][j] = make_float4(a0, a1, a2, a3);
        BAR_LGKM();
        if (wv >= 2) {   // waves 2,3: identical fixed-order reduce + activate
            const float4 q0 = part[e][bf][0][j];
            const float4 q1 = part[e][bf][1][j];
            const float4 q2 = part[e][bf][2][j];
            const float4 q3 = part[e][bf][3][j];
            const float gi = bias[0] + q0.x + q1.x + q2.x + q3.x;
            const float gf = bias[1] + q0.y + q1.y + q2.y + q3.y;
            const float gg = bias[2] + q0.z + q1.z + q2.z + q3.z;
            const float go = bias[3] + q0.w + q1.w + q2.w + q3.w;
            c = sigm(gf) * c + sigm(gi) * tanhf_(gg);
            h = sigm(go) * tanhf_(c);
        }
        x1a = nx1a; x1b = nx1b;
    }
    if (wv == 2) h1last[(size_t)b * 64 + j] = h;
}

// ---------------------------------------------------------------------------
// Layer-1 backward direction collapses to ONE step at t=T-1 (zero init state),
// then the final FC. One wave per batch element.
// ---------------------------------------------------------------------------
__global__ __launch_bounds__(64, 1) void k_l1r_fc(
    const float* __restrict__ h0in,
    const float* __restrict__ wihr,
    const float* __restrict__ bihr, const float* __restrict__ bhhr,
    const float* __restrict__ h1last,
    const float* __restrict__ fcw, const float* __restrict__ fcb,
    float* __restrict__ out)
{
    const int b = blockIdx.x;
    const int j = threadIdx.x;
    const float* __restrict__ xrow = h0in + ((size_t)b * Tn + (Tn - 1)) * 128;
    const float x1a = xrow[j];
    const float x1b = xrow[64 + j];
    float acc[4];
    #pragma unroll
    for (int g = 0; g < 4; ++g) {
        const int r = g * 64 + j;
        float a = bihr[r] + bhhr[r];
        const float* __restrict__ wr = wihr + (size_t)r * 128;
        #pragma unroll
        for (int d4 = 0; d4 < 16; ++d4) {
            const float4 w4 = *reinterpret_cast<const float4*>(&wr[d4 * 4]);
            a = fmaf(rlane(x1a, d4 * 4 + 0), w4.x, a);
            a = fmaf(rlane(x1a, d4 * 4 + 1), w4.y, a);
            a = fmaf(rlane(x1a, d4 * 4 + 2), w4.z, a);
            a = fmaf(rlane(x1a, d4 * 4 + 3), w4.w, a);
        }
        #pragma unroll
        for (int d4 = 0; d4 < 16; ++d4) {
            const float4 w4 = *reinterpret_cast<const float4*>(&wr[64 + d4 * 4]);
            a = fmaf(rlane(x1b, d4 * 4 + 0), w4.x, a);
            a = fmaf(rlane(x1b, d4 * 4 + 1), w4.y, a);
            a = fmaf(rlane(x1b, d4 * 4 + 2), w4.z, a);
            a = fmaf(rlane(x1b, d4 * 4 + 3), w4.w, a);
        }
        acc[g] = a;
    }
    const float cr = sigm(acc[0]) * tanhf_(acc[2]);
    const float hr = sigm(acc[3]) * tanhf_(cr);
    float v = h1last[(size_t)b * 64 + j] * fcw[j] + hr * fcw[64 + j];
    #pragma unroll
    for (int off = 32; off > 0; off >>= 1) v += __shfl_xor(v, off, 64);
    if (j == 0) out[b] = v + fcb[0];
}

// ---------------------------------------------------------------------------
extern "C" void kernel_launch(void* const* d_in, const int* in_sizes, int n_in,
                              void* d_out, int out_size, void* d_ws, size_t ws_size,
                              hipStream_t stream)
{
    const float* x       = (const float*)d_in[0];
    const float* wih_l0  = (const float*)d_in[1];
    const float* whh_l0  = (const float*)d_in[2];
    const float* bih_l0  = (const float*)d_in[3];
    const float* bhh_l0  = (const float*)d_in[4];
    const float* wih_l0r = (const float*)d_in[5];
    const float* whh_l0r = (const float*)d_in[6];
    const float* bih_l0r = (const float*)d_in[7];
    const float* bhh_l0r = (const float*)d_in[8];
    const float* wih_l1  = (const float*)d_in[9];
    const float* whh_l1  = (const float*)d_in[10];
    const float* bih_l1  = (const float*)d_in[11];
    const float* bhh_l1  = (const float*)d_in[12];
    const float* wih_l1r = (const float*)d_in[13];
    const float* whh_l1r = (const float*)d_in[14];
    const float* bih_l1r = (const float*)d_in[15];
    const float* bhh_l1r = (const float*)d_in[16];
    const float* fcw     = (const float*)d_in[17];
    const float* fcb     = (const float*)d_in[18];
    (void)whh_l1r; (void)in_sizes; (void)n_in; (void)out_size; (void)ws_size;

    // ws layout: h0 [512][512][128] f32 (134.2 MB) + h1last [512][64] f32
    float* h0     = (float*)d_ws;
    float* h1last = h0 + (size_t)Bn * Tn * 128;

    k_lstm_l0<<<dim3(Bn), dim3(64), 0, stream>>>(      // 512 blocks: (pair, dir)
        x, wih_l0, whh_l0, bih_l0, bhh_l0,
        wih_l0r, whh_l0r, bih_l0r, bhh_l0r, h0);
    k_lstm_l1f<<<dim3(Bn / 2), dim3(512), 0, stream>>>(
        h0, wih_l1, whh_l1, bih_l1, bhh_l1, h1last);
    k_l1r_fc<<<dim3(Bn), dim3(64), 0, stream>>>(
        h0, wih_l1r, bih_l1r, bhh_l1r, h1last, fcw, fcb, (float*)d_out);
}